// Round 3
// baseline (1306.597 us; speedup 1.0000x reference)
//
#include <hip/hip_runtime.h>
#include <cmath>

// Problem constants
#define CN   256   // channels (N_DIST)
#define HN   256   // H
#define WN   192   // W
#define KN   129   // kernel taps
#define RN   64    // radius
#define SN   256   // padded size
#define PADN 32    // (SN - WN)/2

// ================= conv along W (last axis), LDS-tiled =================
// Block: 256 thr = 4 waves. Tile: 64 rows x 64 output cols; lane = row.
// LDS window pitch 193 (odd): lane-strided reads hit banks (l+pos)%32 -> free.
// Coefficients staged in LDS too: inner loop is DS-only (in-order lgkm).
// 32-entry register window: ds_read refill consumed 16 steps later.
template <int WD, bool ACC>
__global__ __launch_bounds__(256) void conv_w_lds(const float* __restrict__ in,
                                                  const float* __restrict__ kern,
                                                  float* __restrict__ out) {
    __shared__ float lds[64 * 193 + 132];
    float* __restrict__ ldsK = lds + 64 * 193;
    const int tid = threadIdx.x;
    const int x0  = blockIdx.x * 64;
    const int h0  = blockIdx.y * 64;
    const int c   = blockIdx.z;
    const float* __restrict__ in_c = in + ((size_t)c * HN + h0) * WD;

    // stage 64 rows x 192 window cols (global cols x0-64 .. x0+127), zeros outside
    for (int idx = tid; idx < 64 * 192; idx += 256) {
        int r = idx / 192, col = idx - r * 192;
        int g = x0 + col - 64;
        float v = (g >= 0 && g < WD) ? in_c[(size_t)r * WD + g] : 0.f;
        lds[r * 193 + col] = v;
    }
    if (tid < KN) ldsK[tid] = kern[c * KN + tid];
    __syncthreads();

    const int wv = tid >> 6;        // wave 0..3 -> output col chunk
    const int l  = tid & 63;        // lane = row
    const int base = l * 193 + wv * 16;   // window element 0

    const float4* __restrict__ ldsK4 = (const float4*)ldsK;

    float w[32], acc[16];
#pragma unroll
    for (int i = 0; i < 32; ++i) w[i] = lds[base + i];
#pragma unroll
    for (int t = 0; t < 16; ++t) acc[t] = 0.f;

    float kc[16];
#pragma unroll
    for (int q = 0; q < 4; ++q) {
        float4 kv = ldsK4[q];
        kc[4*q] = kv.x; kc[4*q+1] = kv.y; kc[4*q+2] = kv.z; kc[4*q+3] = kv.w;
    }

#pragma unroll
    for (int chunk = 0; chunk < 8; ++chunk) {
        float kn[16];
        if (chunk < 7) {
#pragma unroll
            for (int q = 0; q < 4; ++q) {
                float4 kv = ldsK4[(chunk + 1) * 4 + q];
                kn[4*q] = kv.x; kn[4*q+1] = kv.y; kn[4*q+2] = kv.z; kn[4*q+3] = kv.w;
            }
        }
#pragma unroll
        for (int u = 0; u < 16; ++u) {
            const int j = chunk * 16 + u;
#pragma unroll
            for (int t = 0; t < 16; ++t)
                acc[t] = fmaf(w[(j + t) & 31], kc[u], acc[t]);
            if (chunk < 7) w[j & 31] = lds[base + j + 32];  // consumed 16 steps later
        }
        if (chunk < 7) {
#pragma unroll
            for (int i = 0; i < 16; ++i) kc[i] = kn[i];
        }
    }
    {   // final tap j = 128 (elements 128..143 live in slots 0..15)
        const float k128 = ldsK[128];
#pragma unroll
        for (int t = 0; t < 16; ++t)
            acc[t] = fmaf(w[(128 + t) & 31], k128, acc[t]);
    }

    float* __restrict__ orow = out + ((size_t)c * HN + h0 + l) * WD + x0 + wv * 16;
#pragma unroll
    for (int t = 0; t < 16; ++t) {
        if (ACC) orow[t] += acc[t];
        else     orow[t]  = acc[t];
    }
}

// ================= conv along H (axis 1), LDS-tiled =================
// Block: 256 thr = 4 waves. Tile: 64 output rows x 64 cols; lane = col.
__global__ __launch_bounds__(256) void conv_h_lds(const float* __restrict__ in,
                                                  const float* __restrict__ kern,
                                                  float* __restrict__ out) {
    __shared__ float lds[192 * 64 + 132];
    float* __restrict__ ldsK = lds + 192 * 64;
    const int tid = threadIdx.x;
    const int x0  = blockIdx.x * 64;
    const int h0  = blockIdx.y * 64;
    const int c   = blockIdx.z;
    const float* __restrict__ in_c = in + (size_t)c * HN * WN;

    // stage rows h0-64 .. h0+127 x 64 cols, zeros outside [0,HN)
    for (int idx = tid; idx < 192 * 64; idx += 256) {
        int r = idx >> 6, col = idx & 63;
        int g = h0 + r - 64;
        float v = (g >= 0 && g < HN) ? in_c[(size_t)g * WN + x0 + col] : 0.f;
        lds[r * 64 + col] = v;
    }
    if (tid < KN) ldsK[tid] = kern[c * KN + tid];
    __syncthreads();

    const int wv = tid >> 6;        // wave -> output row chunk
    const int l  = tid & 63;        // lane = col
    const int baseRow = wv * 16;

    const float4* __restrict__ ldsK4 = (const float4*)ldsK;

    float w[32], acc[16];
#pragma unroll
    for (int i = 0; i < 32; ++i) w[i] = lds[(baseRow + i) * 64 + l];
#pragma unroll
    for (int t = 0; t < 16; ++t) acc[t] = 0.f;

    float kc[16];
#pragma unroll
    for (int q = 0; q < 4; ++q) {
        float4 kv = ldsK4[q];
        kc[4*q] = kv.x; kc[4*q+1] = kv.y; kc[4*q+2] = kv.z; kc[4*q+3] = kv.w;
    }

#pragma unroll
    for (int chunk = 0; chunk < 8; ++chunk) {
        float kn[16];
        if (chunk < 7) {
#pragma unroll
            for (int q = 0; q < 4; ++q) {
                float4 kv = ldsK4[(chunk + 1) * 4 + q];
                kn[4*q] = kv.x; kn[4*q+1] = kv.y; kn[4*q+2] = kv.z; kn[4*q+3] = kv.w;
            }
        }
#pragma unroll
        for (int u = 0; u < 16; ++u) {
            const int j = chunk * 16 + u;
#pragma unroll
            for (int t = 0; t < 16; ++t)
                acc[t] = fmaf(w[(j + t) & 31], kc[u], acc[t]);
            if (chunk < 7) w[j & 31] = lds[(baseRow + j + 32) * 64 + l];
        }
        if (chunk < 7) {
#pragma unroll
            for (int i = 0; i < 16; ++i) kc[i] = kn[i];
        }
    }
    {
        const float k128 = ldsK[128];
#pragma unroll
        for (int t = 0; t < 16; ++t)
            acc[t] = fmaf(w[(128 + t) & 31], k128, acc[t]);
    }

    float* __restrict__ ob = out + ((size_t)c * HN + h0 + wv * 16) * WN + x0 + l;
#pragma unroll
    for (int t = 0; t < 16; ++t) ob[(size_t)t * WN] = acc[t];
}

// ---------------- forward rotate of implicitly-padded C ----------------
// 4 outputs per thread along j (spaced 32) -> 16 gathers in flight.
__global__ __launch_bounds__(256) void rot_fwd_k(const float* __restrict__ Cin,
                                                 float* __restrict__ out,
                                                 float ca, float sa) {
    const int jb = blockIdx.x * 128 + threadIdx.x;  // + q*32
    const int i  = blockIdx.y * 8 + threadIdx.y;    // 0..255
    const int c  = blockIdx.z;
    const float cc = (SN - 1) * 0.5f;               // 127.5
    const float yy = (float)i - cc;
    const float* __restrict__ base = Cin + (size_t)c * HN * WN;
    float* __restrict__ orow = out + ((size_t)c * SN + i) * SN;
#pragma unroll
    for (int q = 0; q < 4; ++q) {
        const int j = jb + q * 32;
        float xx = (float)j - cc;
        float sy = ca * yy + sa * xx + cc;
        float sx = -sa * yy + ca * xx + cc;
        float y0f = floorf(sy), x0f = floorf(sx);
        float fy = sy - y0f, fx = sx - x0f;
        int y0 = (int)y0f, x0 = (int)x0f;
        auto g = [&](int yi, int xi) -> float {
            int p = xi - PADN;
            return (yi >= 0 && yi < SN && p >= 0 && p < WN)
                       ? base[(size_t)yi * WN + p] : 0.f;
        };
        float v = g(y0, x0) * (1.f - fy) * (1.f - fx)
                + g(y0, x0 + 1) * (1.f - fy) * fx
                + g(y0 + 1, x0) * fy * (1.f - fx)
                + g(y0 + 1, x0 + 1) * fy * fx;
        orow[j] = v;
    }
}

// ---------------- inverse rotate + accumulate into cropped acc -------------
// 2 outputs per thread along xc (spaced 32) -> 8 gathers in flight.
__global__ __launch_bounds__(256) void rot_bwd_k(const float* __restrict__ U,
                                                 float* __restrict__ acc,
                                                 float ca, float sa) {
    const int xb = blockIdx.x * 64 + threadIdx.x;  // + q*32
    const int i  = blockIdx.y * 8 + threadIdx.y;   // 0..255
    const int c  = blockIdx.z;
    const float cc = (SN - 1) * 0.5f;
    const float yy = (float)i - cc;
    const float* __restrict__ base = U + (size_t)c * SN * SN;
    float* __restrict__ arow = acc + ((size_t)c * HN + i) * WN;
#pragma unroll
    for (int q = 0; q < 2; ++q) {
        const int xc = xb + q * 32;
        const int j  = xc + PADN;
        float xx = (float)j - cc;
        float sy = ca * yy + sa * xx + cc;
        float sx = -sa * yy + ca * xx + cc;
        float y0f = floorf(sy), x0f = floorf(sx);
        float fy = sy - y0f, fx = sx - x0f;
        int y0 = (int)y0f, x0 = (int)x0f;
        auto g = [&](int yi, int xi) -> float {
            return (yi >= 0 && yi < SN && xi >= 0 && xi < SN)
                       ? base[(size_t)yi * SN + xi] : 0.f;
        };
        float v = g(y0, x0) * (1.f - fy) * (1.f - fx)
                + g(y0, x0 + 1) * (1.f - fy) * fx
                + g(y0 + 1, x0) * fy * (1.f - fx)
                + g(y0 + 1, x0 + 1) * fy * fx;
        arow[xc] += v;
    }
}

// ---------------- finalize: out = (C + acc) / norm[c], float4 ----------------
__global__ __launch_bounds__(256) void final_k(float* __restrict__ outC,
                                               const float* __restrict__ acc,
                                               const float* __restrict__ norm) {
    size_t i4 = (size_t)blockIdx.x * 256 + threadIdx.x;
    int c = (int)(i4 / (HN * WN / 4));
    float4* o4 = (float4*)outC;
    const float4* a4 = (const float4*)acc;
    float inv = 1.f / norm[c];
    float4 o = o4[i4], a = a4[i4];
    o.x = (o.x + a.x) * inv; o.y = (o.y + a.y) * inv;
    o.z = (o.z + a.z) * inv; o.w = (o.w + a.w) * inv;
    o4[i4] = o;
}

extern "C" void kernel_launch(void* const* d_in, const int* in_sizes, int n_in,
                              void* d_out, int out_size, void* d_ws, size_t ws_size,
                              hipStream_t stream) {
    const float* x    = (const float*)d_in[0];
    const float* kg   = (const float*)d_in[1];
    const float* kw   = (const float*)d_in[2];
    const float* kiso = (const float*)d_in[3];
    const float* norm = (const float*)d_in[4];

    float* C = (float*)d_out;                 // 256*256*192 floats
    float* ws = (float*)d_ws;
    const size_t IMG = (size_t)CN * HN * WN;  // 12,582,912
    const size_t PSQ = (size_t)CN * SN * SN;  // 16,777,216
    float* B   = ws;                          // IMG
    float* acc = ws + IMG;                    // IMG
    float* T   = ws + 2 * IMG;                // PSQ
    float* U   = T + PSQ;                     // PSQ

    const dim3 blk256(256);
    const dim3 convHGrid(WN / 64, HN / 64, CN);
    const dim3 convW192Grid(WN / 64, HN / 64, CN);
    const dim3 convW256Grid(SN / 64, HN / 64, CN);
    const dim3 rotFGrid(SN / 128, SN / 8, CN), rotBlk(32, 8);
    const dim3 rotBGrid(WN / 64, SN / 8, CN);

    // 1-2: gaussian separable conv -> C (d_out)
    conv_h_lds<<<convHGrid, blk256, 0, stream>>>(x, kg, B);
    conv_w_lds<WN, false><<<convW192Grid, blk256, 0, stream>>>(B, kg, C);
    // 3-4: iso separable conv -> acc
    conv_h_lds<<<convHGrid, blk256, 0, stream>>>(C, kiso, B);
    conv_w_lds<WN, false><<<convW192Grid, blk256, 0, stream>>>(B, kiso, acc);
    // 5: i=0 tail term (identity rotation): acc += conv_w(C, kw)
    conv_w_lds<WN, true><<<convW192Grid, blk256, 0, stream>>>(C, kw, acc);
    // 6-11: i=1,2 tail terms
    const double a1 = 60.0 * M_PI / 180.0, a2 = 120.0 * M_PI / 180.0;
    const float c1 = (float)cos(a1), s1 = (float)sin(a1);
    const float c2 = (float)cos(a2), s2 = (float)sin(a2);

    rot_fwd_k<<<rotFGrid, rotBlk, 0, stream>>>(C, T, c1, s1);
    conv_w_lds<SN, false><<<convW256Grid, blk256, 0, stream>>>(T, kw, U);
    rot_bwd_k<<<rotBGrid, rotBlk, 0, stream>>>(U, acc, c1, -s1);

    rot_fwd_k<<<rotFGrid, rotBlk, 0, stream>>>(C, T, c2, s2);
    conv_w_lds<SN, false><<<convW256Grid, blk256, 0, stream>>>(T, kw, U);
    rot_bwd_k<<<rotBGrid, rotBlk, 0, stream>>>(U, acc, c2, -s2);

    // 12: out = (C + acc) / norm[c]
    final_k<<<(unsigned)(IMG / 4 / 256), blk256, 0, stream>>>(C, acc, norm);
    (void)in_sizes; (void)n_in; (void)out_size; (void)ws_size;
}